// Round 9
// baseline (622.735 us; speedup 1.0000x reference)
//
#include <hip/hip_runtime.h>
#include <hip/hip_fp16.h>
#include <math.h>

#define NN 50000
#define NNP 50048
#define EE 800000
#define IN_F 200
#define DD 127
#define GG 512
#define EPSH 1e-5f
#define PS_SCALE 0.015625f  // 2^-6 pre-scale on H points (centroid is scale-invariant)

typedef unsigned int u32;
typedef unsigned short u16;
typedef __attribute__((ext_vector_type(8))) short short8;
typedef __attribute__((ext_vector_type(4))) float f32x4;
typedef _Float16 h2f __attribute__((ext_vector_type(2)));
typedef __fp16 fp16x2 __attribute__((ext_vector_type(2)));
union UH {
  u32 u;
  h2f h;
  fp16x2 f;
};

__device__ __forceinline__ u32 bf16r(float x) {
  u32 u = __float_as_uint(x);
  return (u + 0x7fffu + ((u >> 16) & 1u)) >> 16;
}

__device__ __forceinline__ u32 packhl(float v) {  // u32 = bf16_hi | bf16_lo<<16
  u32 hi = bf16r(v);
  float vh = __uint_as_float(hi << 16);
  u32 lo = bf16r(v - vh);
  return hi | (lo << 16);
}

__device__ __forceinline__ float rec(u32 u) {
  return __uint_as_float(u << 16) + __uint_as_float(u & 0xffff0000u);
}

__device__ __forceinline__ u32 pk2h(float a, float b) {  // packed half2 bits
#if __has_builtin(__builtin_amdgcn_cvt_pkrtz)
  UH x;
  x.f = __builtin_amdgcn_cvt_pkrtz(a, b);
  return x.u;
#else
  __half2 r = __floats2half2_rn(a, b);
  return *(u32*)&r;
#endif
}

__device__ __forceinline__ float fdot2h(u32 a, u32 b, float acc) {
  UH ua, ub;
  ua.u = a;
  ub.u = b;
#if __has_builtin(__builtin_amdgcn_fdot2)
  return __builtin_amdgcn_fdot2(ua.h, ub.h, acc, false);
#else
  acc = fmaf((float)ua.h[0], (float)ub.h[0], acc);
  return fmaf((float)ua.h[1], (float)ub.h[1], acc);
#endif
}

// ---------------- prep: weights -> bf16 hi/lo fragment layout ----------------
#define WF_TOT (28672 + 6 * 16384)
__global__ void k_prep_wf(const float* __restrict__ att_w, const float* __restrict__ mlp_w,
                          const float* __restrict__ w_in, u16* __restrict__ Wfh,
                          u16* __restrict__ Wfl) {
  for (int idx = blockIdx.x * 256 + threadIdx.x; idx < WF_TOT; idx += gridDim.x * 256) {
    float val;
    if (idx < 28672) {
      int q = idx >> 12, rem = idx & 4095;
      int t = rem >> 9, l = (rem >> 3) & 63, j = rem & 7;
      int k = q * 32 + ((l >> 4) << 3) + j, n = t * 16 + (l & 15);
      val = (k < IN_F && n < DD) ? w_in[k * DD + n] : 0.f;
    } else {
      int rel = idx - 28672;
      int mat = rel >> 14, rem = rel & 16383;
      int q = rem >> 12;
      rem &= 4095;
      int t = rem >> 9, l = (rem >> 3) & 63, j = rem & 7;
      int k = q * 32 + ((l >> 4) << 3) + j, n = t * 16 + (l & 15);
      const float* wsrc = (mat < 2) ? att_w + mat * DD * DD : mlp_w + (mat - 2) * DD * DD;
      val = (k < DD && n < DD) ? wsrc[n * DD + k] : 0.f;
    }
    u32 hi = bf16r(val);
    float vh = __uint_as_float(hi << 16);
    u32 lo = bf16r(val - vh);
    Wfh[idx] = (u16)hi;
    Wfl[idx] = (u16)lo;
  }
}

// ---------------- CSR build ----------------
__global__ void k_count(const int* __restrict__ idx, int n, int* __restrict__ cnt) {
  int i = blockIdx.x * blockDim.x + threadIdx.x;
  if (i < n) atomicAdd(&cnt[idx[i]], 1);
}

__global__ __launch_bounds__(1024) void k_scan_excl(const int* __restrict__ in, int n,
                                                    int* __restrict__ out, int* __restrict__ cur) {
  __shared__ int wbase[16];
  __shared__ int chunk_tot;
  int tid = threadIdx.x;
  int lane = tid & 63;
  int w = tid >> 6;
  int carry = 0;
  for (int base = 0; base < n; base += 4096) {
    int i0 = base + tid * 4;
    int v[4];
#pragma unroll
    for (int j = 0; j < 4; j++) v[j] = (i0 + j < n) ? in[i0 + j] : 0;
    int x = v[0] + v[1] + v[2] + v[3];
    int incl = x;
#pragma unroll
    for (int off = 1; off < 64; off <<= 1) {
      int t = __shfl_up(incl, off);
      if (lane >= off) incl += t;
    }
    if (lane == 63) wbase[w] = incl;
    __syncthreads();
    if (w == 0) {
      int t = (lane < 16) ? wbase[lane] : 0;
      int it = t;
#pragma unroll
      for (int off = 1; off < 16; off <<= 1) {
        int v2 = __shfl_up(it, off);
        if (lane >= off) it += v2;
      }
      if (lane < 16) wbase[lane] = it - t;
      if (lane == 15) chunk_tot = it;
    }
    __syncthreads();
    int run = carry + wbase[w] + (incl - x);
#pragma unroll
    for (int j = 0; j < 4; j++) {
      if (i0 + j < n) {
        out[i0 + j] = run;
        if (cur) cur[i0 + j] = run;
      }
      run += v[j];
    }
    carry += chunk_tot;
    __syncthreads();
  }
  if (tid == 0) out[n] = carry;
}

__global__ void k_scatter(const int* __restrict__ src, const int* __restrict__ dst, int n,
                          int* __restrict__ cursor, int* __restrict__ dst_sorted) {
  int e = blockIdx.x * blockDim.x + threadIdx.x;
  if (e < n) {
    int s = src[e];
    int slot = atomicAdd(&cursor[s], 1);
    dst_sorted[slot] = dst[e];
  }
}

__global__ void k_gptr(const int* __restrict__ batch, int* __restrict__ gptr) {
  int g = blockIdx.x * blockDim.x + threadIdx.x;
  if (g > GG) return;
  int lo = 0, hi = NN;
  while (lo < hi) {
    int mid = (lo + hi) >> 1;
    if (batch[mid] < g) lo = mid + 1; else hi = mid;
  }
  gptr[g] = lo;
}

// ---------------- MFMA building blocks ----------------
union AB {
  short8 v;
  u32 w[4];
};

__device__ __forceinline__ void build_hl(const float* xv, AB& ah, AB& al) {
#pragma unroll
  for (int p = 0; p < 4; p++) {
    u32 h0 = bf16r(xv[2 * p]), h1 = bf16r(xv[2 * p + 1]);
    float f0 = __uint_as_float(h0 << 16), f1 = __uint_as_float(h1 << 16);
    ah.w[p] = h0 | (h1 << 16);
    al.w[p] = bf16r(xv[2 * p] - f0) | (bf16r(xv[2 * p + 1] - f1) << 16);
  }
}

__device__ __forceinline__ void mfma3(const AB& ah, const AB& al, const u16* __restrict__ Wh,
                                      const u16* __restrict__ Wl, int q, int lane, f32x4* acc) {
  const u16* bph = Wh + ((size_t)(q * 8) * 64 + lane) * 8;
  const u16* bpl = Wl + ((size_t)(q * 8) * 64 + lane) * 8;
#pragma unroll
  for (int t = 0; t < 8; t++) {
    short8 bh = *(const short8*)(bph + t * 512);
    short8 bl = *(const short8*)(bpl + t * 512);
    acc[t] = __builtin_amdgcn_mfma_f32_16x16x32_bf16(ah.v, bh, acc[t], 0, 0, 0);
    acc[t] = __builtin_amdgcn_mfma_f32_16x16x32_bf16(al.v, bh, acc[t], 0, 0, 0);
    acc[t] = __builtin_amdgcn_mfma_f32_16x16x32_bf16(ah.v, bl, acc[t], 0, 0, 0);
  }
}

__device__ __forceinline__ void gemm_packhl(const u32* __restrict__ A32, int mld,
                                            const u16* __restrict__ Wh,
                                            const u16* __restrict__ Wl, int lane, int quad,
                                            f32x4* acc) {
#pragma unroll
  for (int q = 0; q < 4; q++) {
    int k0 = q * 32 + quad * 8;
    const u32* ap = A32 + (size_t)mld * 128 + k0;
    uint4 u0 = *(const uint4*)ap;
    uint4 u1 = *(const uint4*)(ap + 4);
    u32 uu[8] = {u0.x, u0.y, u0.z, u0.w, u1.x, u1.y, u1.z, u1.w};
    AB ah, al;
#pragma unroll
    for (int p = 0; p < 4; p++) {
      ah.w[p] = __builtin_amdgcn_perm(uu[2 * p + 1], uu[2 * p], 0x05040100u);
      al.w[p] = __builtin_amdgcn_perm(uu[2 * p + 1], uu[2 * p], 0x07060302u);
    }
    mfma3(ah, al, Wh, Wl, q, lane, acc);
  }
}

__device__ __forceinline__ void gemm_lds(const float (*tile)[129], int ml, int quad, int lane,
                                         const u16* __restrict__ Wh, const u16* __restrict__ Wl,
                                         f32x4* acc) {
#pragma unroll
  for (int q = 0; q < 4; q++) {
    int k0 = q * 32 + quad * 8;
    float xv[8];
#pragma unroll
    for (int j = 0; j < 8; j++) xv[j] = tile[ml][k0 + j];
    AB ah, al;
    build_hl(xv, ah, al);
    mfma3(ah, al, Wh, Wl, q, lane, acc);
  }
}

__device__ __forceinline__ void bias8(const float* __restrict__ bias, int ml, float* bj) {
#pragma unroll
  for (int t = 0; t < 8; t++) {
    int col = t * 16 + ml;
    bj[t] = (bias != nullptr && col < DD) ? bias[col] : 0.f;
  }
}

template <int TANH>
__device__ __forceinline__ void row_vs(const f32x4* acc, const float* bj, int r, float* vs) {
#pragma unroll
  for (int t = 0; t < 8; t++) {
    float v = acc[t][r] + bj[t];
    if (TANH) {
      float e = exp2f(v * 2.8853900817779268f);  // exp(2v)
      v = 1.f - 2.f / (e + 1.f);
    }
    vs[t] = v;
  }
}

__device__ __forceinline__ void store_T_row(const float* vs, u32* __restrict__ To, int rowD,
                                            int ml) {
  u32* to = To + (size_t)rowD * 128 + ml;
#pragma unroll
  for (int t = 0; t < 8; t++) to[t * 16] = packhl(vs[t]);
}

// point store: slot s=t*16+ml holds half2(spatial col s, col s+64); time -> Pt[rowD*2]
__device__ __forceinline__ void store_P_row(const float* vs, u32* __restrict__ Pb,
                                            float* __restrict__ Pt, int rowD, int ml, float cc,
                                            float sc, float pscale) {
  float ps = 0.f;
#pragma unroll
  for (int t = 0; t < 8; t++) ps += vs[t] * vs[t];
#pragma unroll
  for (int off = 1; off < 16; off <<= 1) ps += __shfl_xor(ps, off);
  float nn = fmaxf(sqrtf(ps), 1e-9f);
  float e = expf(nn / sc);
  float f = sc * (e - 1.f / e) * 0.5f / nn;  // sc*sinh(nn/sc)/nn
  float tt = sqrtf(cc + f * f * ps);
  f *= pscale;
  u32* pb = Pb + (size_t)rowD * 128 + ml;
#pragma unroll
  for (int t = 0; t < 4; t++) pb[t * 16] = pk2h(f * vs[t], f * vs[t + 4]);
  if (ml == 0) Pt[rowD * 2] = pscale * tt;
}

// ---------------- fused input GEMM + att-GEMM(layer0) ----------------
__global__ __launch_bounds__(256) void k_gemm_in(
    const float* __restrict__ x, const u16* __restrict__ WhI, const u16* __restrict__ WlI,
    const u16* __restrict__ WhA, const u16* __restrict__ WlA, const float* __restrict__ attb,
    u32* __restrict__ To, u32* __restrict__ HHh, float* __restrict__ ptF,
    const float* __restrict__ cptr, int M) {
  __shared__ float tile[4][16][129];
  int lane = threadIdx.x & 63, wid = threadIdx.x >> 6;
  int m0 = blockIdx.x * 64 + wid * 16;
  int ml = lane & 15, quad = lane >> 4;
  int mld = m0 + ml;
  f32x4 acc[8];
#pragma unroll
  for (int t = 0; t < 8; t++) acc[t] = (f32x4){0.f, 0.f, 0.f, 0.f};
#pragma unroll
  for (int q = 0; q < 7; q++) {
    int k0 = q * 32 + quad * 8;
    bool ok = (mld < M) && (k0 + 7 < IN_F);
    const float* ap = x + (size_t)mld * IN_F + k0;
    float4 x0 = ok ? *(const float4*)ap : make_float4(0.f, 0.f, 0.f, 0.f);
    float4 x1 = ok ? *(const float4*)(ap + 4) : make_float4(0.f, 0.f, 0.f, 0.f);
    float xv[8] = {x0.x, x0.y, x0.z, x0.w, x1.x, x1.y, x1.z, x1.w};
    AB ah, al;
    build_hl(xv, ah, al);
    mfma3(ah, al, WhI, WlI, q, lane, acc);
  }
  float cc = *cptr, sc = sqrtf(cc);
  {
    float bj[8];
    bias8(nullptr, ml, bj);
#pragma unroll
    for (int r = 0; r < 4; r++) {
      int rowD = m0 + quad * 4 + r;
      float vs[8];
      row_vs<0>(acc, bj, r, vs);
      if (rowD < M) {
        store_T_row(vs, To, rowD, ml);
        store_P_row(vs, HHh + 64, ptF + 1, rowD, ml, cc, sc, PS_SCALE);
      }
#pragma unroll
      for (int t = 0; t < 8; t++) tile[wid][quad * 4 + r][t * 16 + ml] = vs[t];
    }
  }
#pragma unroll
  for (int t = 0; t < 8; t++) acc[t] = (f32x4){0.f, 0.f, 0.f, 0.f};
  gemm_lds(tile[wid], ml, quad, lane, WhA, WlA, acc);
  {
    float bj[8];
    bias8(attb, ml, bj);
#pragma unroll
    for (int r = 0; r < 4; r++) {
      int rowD = m0 + quad * 4 + r;
      float vs[8];
      row_vs<0>(acc, bj, r, vs);
      if (rowD < M) store_P_row(vs, HHh, ptF, rowD, ml, cc, sc, 1.f);
    }
  }
}

// ---------------- fused MLP pair (+ next layer's att GEMM unless LAST) ----------------
template <int LAST>
__global__ __launch_bounds__(256) void k_mlp3(
    const u32* __restrict__ A32, const u16* __restrict__ Wha, const u16* __restrict__ Wla,
    const float* __restrict__ ba, const u16* __restrict__ Whb, const u16* __restrict__ Wlb,
    const float* __restrict__ bb, const u16* __restrict__ WhA, const u16* __restrict__ WlA,
    const float* __restrict__ attb, u32* __restrict__ To, u32* __restrict__ HHh,
    float* __restrict__ ptF, const float* __restrict__ cptr, int M) {
  __shared__ float tile[4][16][129];
  int lane = threadIdx.x & 63, wid = threadIdx.x >> 6;
  int m0 = blockIdx.x * 64 + wid * 16;
  int ml = lane & 15, quad = lane >> 4;
  int mld = m0 + ml;
  f32x4 acc[8];
#pragma unroll
  for (int t = 0; t < 8; t++) acc[t] = (f32x4){0.f, 0.f, 0.f, 0.f};
  gemm_packhl(A32, mld, Wha, Wla, lane, quad, acc);
  {
    float bj[8];
    bias8(ba, ml, bj);
#pragma unroll
    for (int r = 0; r < 4; r++) {
      float vs[8];
      row_vs<1>(acc, bj, r, vs);
#pragma unroll
      for (int t = 0; t < 8; t++) tile[wid][quad * 4 + r][t * 16 + ml] = vs[t];
    }
  }
#pragma unroll
  for (int t = 0; t < 8; t++) acc[t] = (f32x4){0.f, 0.f, 0.f, 0.f};
  gemm_lds(tile[wid], ml, quad, lane, Whb, Wlb, acc);
  float cc = 1.f, sc = 1.f;
  if (!LAST) {
    cc = *cptr;
    sc = sqrtf(cc);
  }
  {
    float bj[8];
    bias8(bb, ml, bj);
#pragma unroll
    for (int r = 0; r < 4; r++) {
      int rowD = m0 + quad * 4 + r;
      float vs[8];
      row_vs<1>(acc, bj, r, vs);
      if (rowD < M) store_T_row(vs, To, rowD, ml);
      if (!LAST) {
        if (rowD < M) store_P_row(vs, HHh + 64, ptF + 1, rowD, ml, cc, sc, PS_SCALE);
#pragma unroll
        for (int t = 0; t < 8; t++) tile[wid][quad * 4 + r][t * 16 + ml] = vs[t];
      }
    }
  }
  if (!LAST) {
#pragma unroll
    for (int t = 0; t < 8; t++) acc[t] = (f32x4){0.f, 0.f, 0.f, 0.f};
    gemm_lds(tile[wid], ml, quad, lane, WhA, WlA, acc);
    float bj[8];
    bias8(attb, ml, bj);
#pragma unroll
    for (int r = 0; r < 4; r++) {
      int rowD = m0 + quad * 4 + r;
      float vs[8];
      row_vs<0>(acc, bj, r, vs);
      if (rowD < M) store_P_row(vs, HHh, ptF, rowD, ml, cc, sc, 1.f);
    }
  }
}

// ---------------- fused attention + aggregation, 4-lane edge groups ----------------
// HHh row (128 u32): [0..63] HL half2 (cols s, s+64); [64..127] H half2 * 2^-6.
// ptHH[node] = (time(HL), time(H)*2^-6). 16 edges in flight per wave.
__global__ __launch_bounds__(256) void k_agg_o(const u32* __restrict__ HHh,
                                               const float2* __restrict__ ptHH,
                                               const u32* __restrict__ T,
                                               const int* __restrict__ rowp,
                                               const int* __restrict__ dsts,
                                               const float* __restrict__ epsp,
                                               const float* __restrict__ cptr,
                                               u32* __restrict__ Tout, int n) {
  int node = blockIdx.x * 4 + (threadIdx.x >> 6);
  int lane = threadIdx.x & 63;
  if (node >= n) return;
  int o = lane & 3;   // slot group: u32 slots o*16 .. o*16+15
  int g = lane >> 2;  // edge group 0..15
  float c = *cptr, sc = sqrtf(c), rcpc = 1.f / c;
  float eps = *epsp;
  const u32* arow = HHh + (size_t)node * 128 + o * 16;
  u32 apk[16];
  {
    uint4 a0 = *(const uint4*)arow;
    uint4 a1 = *(const uint4*)(arow + 4);
    uint4 a2 = *(const uint4*)(arow + 8);
    uint4 a3 = *(const uint4*)(arow + 12);
    apk[0] = a0.x; apk[1] = a0.y; apk[2] = a0.z; apk[3] = a0.w;
    apk[4] = a1.x; apk[5] = a1.y; apk[6] = a1.z; apk[7] = a1.w;
    apk[8] = a2.x; apk[9] = a2.y; apk[10] = a2.z; apk[11] = a2.w;
    apk[12] = a3.x; apk[13] = a3.y; apk[14] = a3.z; apk[15] = a3.w;
  }
  float pts = ptHH[node].x;
  int e0 = rowp[node], e1 = rowp[node + 1];
  int iters = (e1 - e0 + 15) >> 4;
  h2f mpk[16];
  {
    UH z;
    z.u = 0;
#pragma unroll
    for (int j = 0; j < 16; j++) mpk[j] = z.h;
  }
  float mt = 0.f;
  for (int it = 0; it < iters; it++) {
    int e = e0 + it * 16 + g;
    bool ve = e < e1;
    int d = dsts[ve ? e : e0];
    const u32* rb = HHh + (size_t)d * 128 + o * 16;
    uint4 b0 = *(const uint4*)rb;
    uint4 b1 = *(const uint4*)(rb + 4);
    uint4 b2 = *(const uint4*)(rb + 8);
    uint4 b3 = *(const uint4*)(rb + 12);
    uint4 h0 = *(const uint4*)(rb + 64);
    uint4 h1 = *(const uint4*)(rb + 68);
    uint4 h2 = *(const uint4*)(rb + 72);
    uint4 h3 = *(const uint4*)(rb + 76);
    float2 pp = ptHH[d];
    u32 bw[16] = {b0.x, b0.y, b0.z, b0.w, b1.x, b1.y, b1.z, b1.w,
                  b2.x, b2.y, b2.z, b2.w, b3.x, b3.y, b3.z, b3.w};
    float dot = 0.f;
#pragma unroll
    for (int j = 0; j < 16; j++) dot = fdot2h(apk[j], bw[j], dot);
    dot += __shfl_xor(dot, 1);
    dot += __shfl_xor(dot, 2);
    float valv = fmaxf((pts * pp.x - dot) * rcpc, 1.f + EPSH);
    float w = valv + sqrtf(fmaf(valv, valv, -1.f));
    float att = exp2f(-sc * __log2f(w));  // exp(-sc*acosh(val))
    att = ve ? att : 0.f;
    UH att2;
    att2.u = pk2h(att, att);
    u32 hw[16] = {h0.x, h0.y, h0.z, h0.w, h1.x, h1.y, h1.z, h1.w,
                  h2.x, h2.y, h2.z, h2.w, h3.x, h3.y, h3.z, h3.w};
#pragma unroll
    for (int j = 0; j < 16; j++) {
      UH hv;
      hv.u = hw[j];
      mpk[j] = att2.h * hv.h + mpk[j];  // v_pk_fma_f16
    }
    mt = fmaf(att, pp.y, mt);
  }
  // cross-edge-group reduce (offsets 4,8,16,32)
#pragma unroll
  for (int off = 4; off <= 32; off <<= 1) {
#pragma unroll
    for (int j = 0; j < 16; j++) {
      UH v;
      v.h = mpk[j];
      UH s;
      s.u = (u32)__shfl_xor((int)v.u, off);
      mpk[j] = v.h + s.h;
    }
    mt += __shfl_xor(mt, off);
  }
  // lsq over the full spatial vector (slots partitioned across o; reduce 1,2)
  float lp = 0.f;
#pragma unroll
  for (int j = 0; j < 16; j++) {
    float lo = (float)mpk[j][0], hi = (float)mpk[j][1];
    lp = fmaf(lo, lo, lp);
    lp = fmaf(hi, hi, lp);
  }
  lp += __shfl_xor(lp, 1);
  lp += __shfl_xor(lp, 2);
  float lsq = lp;
  float neg_inner = mt * mt - lsq;
  float denom = sqrtf(fmaxf(neg_inner, 1e-9f));
  float r = sc / denom;
  float ssq = r * r * lsq;
  float agg0 = sqrtf(c + ssq);
  float ynA = fmaxf(sqrtf(ssq), 1e-9f);
  float v2 = fmaxf(agg0 / sc, 1.f + EPSH);
  float dA = sc * 0.69314718056f * __log2f(v2 + sqrtf(v2 * v2 - 1.f));
  float sca = dA * r / ynA;
  if (g == 0) {
    const u32* tp = T + (size_t)node * 128 + o * 16;
    uint4 t0 = *(const uint4*)tp;
    uint4 t1 = *(const uint4*)(tp + 4);
    uint4 t2 = *(const uint4*)(tp + 8);
    uint4 t3 = *(const uint4*)(tp + 12);
    uint4 v0 = *(const uint4*)(tp + 64);
    uint4 v1 = *(const uint4*)(tp + 68);
    uint4 v2q = *(const uint4*)(tp + 72);
    uint4 v3 = *(const uint4*)(tp + 76);
    u32 tw[16] = {t0.x, t0.y, t0.z, t0.w, t1.x, t1.y, t1.z, t1.w,
                  t2.x, t2.y, t2.z, t2.w, t3.x, t3.y, t3.z, t3.w};
    u32 tv[16] = {v0.x, v0.y, v0.z, v0.w, v1.x, v1.y, v1.z, v1.w,
                  v2q.x, v2q.y, v2q.z, v2q.w, v3.x, v3.y, v3.z, v3.w};
    float oe = 1.f + eps;
    u32 olo[16], ohi[16];
#pragma unroll
    for (int j = 0; j < 16; j++) {
      float lo = (float)mpk[j][0], hi = (float)mpk[j][1];
      olo[j] = packhl(fmaf(sca, lo, oe * rec(tw[j])));
      ohi[j] = packhl(fmaf(sca, hi, oe * rec(tv[j])));
    }
    u32* op = Tout + (size_t)node * 128 + o * 16;
#pragma unroll
    for (int j = 0; j < 4; j++) {
      *(uint4*)(op + j * 4) = make_uint4(olo[4 * j], olo[4 * j + 1], olo[4 * j + 2], olo[4 * j + 3]);
      *(uint4*)(op + 64 + j * 4) = make_uint4(ohi[4 * j], ohi[4 * j + 1], ohi[4 * j + 2], ohi[4 * j + 3]);
    }
  }
}

// ---------------- pooling ----------------
__global__ void k_pool(const u32* __restrict__ U, const int* __restrict__ gptr,
                       float* __restrict__ out, int layer) {
  int g = blockIdx.x;
  int c = threadIdx.x;  // 0..127
  int s = gptr[g], e = gptr[g + 1];
  float acc = 0.f;
  if (c > 0) {
    const u32* up = U + (c - 1);
    int i = s;
    float a0 = 0.f, a1 = 0.f, a2 = 0.f, a3 = 0.f;
    for (; i + 3 < e; i += 4) {
      a0 += rec(up[(size_t)i * 128]);
      a1 += rec(up[(size_t)(i + 1) * 128]);
      a2 += rec(up[(size_t)(i + 2) * 128]);
      a3 += rec(up[(size_t)(i + 3) * 128]);
    }
    for (; i < e; i++) a0 += rec(up[(size_t)i * 128]);
    acc = (a0 + a1) + (a2 + a3);
  }
  out[(size_t)g * 256 + layer * 128 + c] = acc;
}

// ---------------- launch ----------------
extern "C" void kernel_launch(void* const* d_in, const int* in_sizes, int n_in, void* d_out,
                              int out_size, void* d_ws, size_t ws_size, hipStream_t stream) {
  const float* x = (const float*)d_in[0];
  const float* cptr = (const float*)d_in[1];
  const float* w_in = (const float*)d_in[2];
  const float* att_w = (const float*)d_in[3];
  const float* att_b = (const float*)d_in[4];
  const float* epsv = (const float*)d_in[5];
  const float* mlp_w = (const float*)d_in[6];
  const float* mlp_b = (const float*)d_in[7];
  const int* ei = (const int*)d_in[8];
  const int* batch = (const int*)d_in[9];
  const int* srcp = ei;
  const int* dstp = ei + EE;
  float* out = (float*)d_out;

  u32* ws = (u32*)d_ws;
  u16* Wfh = (u16*)ws;  // WF_TOT u16
  u16* Wfl = Wfh + WF_TOT;
  int* deg = (int*)(ws + 126976);  // N
  int* rowp = deg + NN;            // N+1
  int* cursor = rowp + NN + 1;     // N
  int* gptr = cursor + NN;         // G+1
  int* dsts = gptr + GG + 1;       // E
  size_t o1 = (size_t)((u32*)(dsts + EE) - ws);
  o1 = (o1 + 3) & ~(size_t)3;
  float2* ptHH = (float2*)(ws + o1);   // NNP float2
  u32* HHh = ws + o1 + 2 * NNP;        // NNP*128 (HL | H), half2 slots
  u32* A32 = HHh + (size_t)NNP * 128;  // NNP*128 packhl tangent
  u32* B32 = A32 + (size_t)NNP * 128;  // NNP*128

  const int EW = 12500;  // agg: 4 nodes/block
  const int GEMMG = (NN + 63) / 64;
  float* ptF = (float*)ptHH;

  (void)hipMemsetAsync(deg, 0, NN * sizeof(int), stream);
  k_prep_wf<<<64, 256, 0, stream>>>(att_w, mlp_w, w_in, Wfh, Wfl);
  k_count<<<(EE + 255) / 256, 256, 0, stream>>>(srcp, EE, deg);
  k_gptr<<<3, 256, 0, stream>>>(batch, gptr);
  k_scan_excl<<<1, 1024, 0, stream>>>(deg, NN, rowp, cursor);
  k_scatter<<<(EE + 255) / 256, 256, 0, stream>>>(srcp, dstp, EE, cursor, dsts);

#define WH(m) (Wfh + 28672 + (m) * 16384)
#define WL(m) (Wfl + 28672 + (m) * 16384)

  // input GEMM + att0: T0 -> A32 ; H0 -> (HHh+64, ptF odd) ; HL0 -> (HHh, ptF even)
  k_gemm_in<<<GEMMG, 256, 0, stream>>>(x, Wfh, Wfl, WH(0), WL(0), att_b, A32, HHh, ptF, cptr, NN);

  // ---- layer 0 ----
  k_agg_o<<<EW, 256, 0, stream>>>(HHh, ptHH, A32, rowp, dsts, epsv + 0, cptr, B32, NN);
  k_mlp3<0><<<GEMMG, 256, 0, stream>>>(B32, WH(2), WL(2), mlp_b + 0 * DD, WH(3), WL(3),
                                       mlp_b + 1 * DD, WH(1), WL(1), att_b + DD, A32, HHh, ptF,
                                       cptr, NN);
  k_pool<<<GG, 128, 0, stream>>>(A32, gptr, out, 0);

  // ---- layer 1 ----
  k_agg_o<<<EW, 256, 0, stream>>>(HHh, ptHH, A32, rowp, dsts, epsv + 1, cptr, B32, NN);
  k_mlp3<1><<<GEMMG, 256, 0, stream>>>(B32, WH(4), WL(4), mlp_b + 2 * DD, WH(5), WL(5),
                                       mlp_b + 3 * DD, nullptr, nullptr, nullptr, B32, nullptr,
                                       nullptr, cptr, NN);
  k_pool<<<GG, 128, 0, stream>>>(B32, gptr, out, 1);
}

// Round 10
// 556.119 us; speedup vs baseline: 1.1198x; 1.1198x over previous
//
#include <hip/hip_runtime.h>
#include <hip/hip_fp16.h>
#include <math.h>

#define NN 50000
#define NNP 50048
#define EE 800000
#define IN_F 200
#define DD 127
#define GG 512
#define EPSH 1e-5f
#define PS_SCALE 0.015625f  // 2^-6 pre-scale on H points (centroid is scale-invariant)

typedef unsigned int u32;
typedef unsigned short u16;
typedef __attribute__((ext_vector_type(8))) short short8;
typedef __attribute__((ext_vector_type(4))) float f32x4;
typedef _Float16 h2f __attribute__((ext_vector_type(2)));
typedef __fp16 fp16x2 __attribute__((ext_vector_type(2)));
union UH {
  u32 u;
  h2f h;
  fp16x2 f;
};

__device__ __forceinline__ u32 bf16r(float x) {
  u32 u = __float_as_uint(x);
  return (u + 0x7fffu + ((u >> 16) & 1u)) >> 16;
}

__device__ __forceinline__ u32 packhl(float v) {  // u32 = bf16_hi | bf16_lo<<16
  u32 hi = bf16r(v);
  float vh = __uint_as_float(hi << 16);
  u32 lo = bf16r(v - vh);
  return hi | (lo << 16);
}

__device__ __forceinline__ float rec(u32 u) {
  return __uint_as_float(u << 16) + __uint_as_float(u & 0xffff0000u);
}

__device__ __forceinline__ u32 pk2h(float a, float b) {  // packed half2 bits
#if __has_builtin(__builtin_amdgcn_cvt_pkrtz)
  UH x;
  x.f = __builtin_amdgcn_cvt_pkrtz(a, b);
  return x.u;
#else
  __half2 r = __floats2half2_rn(a, b);
  return *(u32*)&r;
#endif
}

__device__ __forceinline__ float fdot2h(u32 a, u32 b, float acc) {
  UH ua, ub;
  ua.u = a;
  ub.u = b;
#if __has_builtin(__builtin_amdgcn_fdot2)
  return __builtin_amdgcn_fdot2(ua.h, ub.h, acc, false);
#else
  acc = fmaf((float)ua.h[0], (float)ub.h[0], acc);
  return fmaf((float)ua.h[1], (float)ub.h[1], acc);
#endif
}

// ---------------- prep: weights -> bf16 hi/lo fragment layout ----------------
#define WF_TOT (28672 + 6 * 16384)
__global__ void k_prep_wf(const float* __restrict__ att_w, const float* __restrict__ mlp_w,
                          const float* __restrict__ w_in, u16* __restrict__ Wfh,
                          u16* __restrict__ Wfl) {
  for (int idx = blockIdx.x * 256 + threadIdx.x; idx < WF_TOT; idx += gridDim.x * 256) {
    float val;
    if (idx < 28672) {
      int q = idx >> 12, rem = idx & 4095;
      int t = rem >> 9, l = (rem >> 3) & 63, j = rem & 7;
      int k = q * 32 + ((l >> 4) << 3) + j, n = t * 16 + (l & 15);
      val = (k < IN_F && n < DD) ? w_in[k * DD + n] : 0.f;
    } else {
      int rel = idx - 28672;
      int mat = rel >> 14, rem = rel & 16383;
      int q = rem >> 12;
      rem &= 4095;
      int t = rem >> 9, l = (rem >> 3) & 63, j = rem & 7;
      int k = q * 32 + ((l >> 4) << 3) + j, n = t * 16 + (l & 15);
      const float* wsrc = (mat < 2) ? att_w + mat * DD * DD : mlp_w + (mat - 2) * DD * DD;
      val = (k < DD && n < DD) ? wsrc[n * DD + k] : 0.f;
    }
    u32 hi = bf16r(val);
    float vh = __uint_as_float(hi << 16);
    u32 lo = bf16r(val - vh);
    Wfh[idx] = (u16)hi;
    Wfl[idx] = (u16)lo;
  }
}

// ---------------- CSR build ----------------
__global__ void k_count(const int* __restrict__ idx, int n, int* __restrict__ cnt) {
  int i = blockIdx.x * blockDim.x + threadIdx.x;
  if (i < n) atomicAdd(&cnt[idx[i]], 1);
}

__global__ __launch_bounds__(1024) void k_scan_excl(const int* __restrict__ in, int n,
                                                    int* __restrict__ out, int* __restrict__ cur) {
  __shared__ int wbase[16];
  __shared__ int chunk_tot;
  int tid = threadIdx.x;
  int lane = tid & 63;
  int w = tid >> 6;
  int carry = 0;
  for (int base = 0; base < n; base += 4096) {
    int i0 = base + tid * 4;
    int v[4];
#pragma unroll
    for (int j = 0; j < 4; j++) v[j] = (i0 + j < n) ? in[i0 + j] : 0;
    int x = v[0] + v[1] + v[2] + v[3];
    int incl = x;
#pragma unroll
    for (int off = 1; off < 64; off <<= 1) {
      int t = __shfl_up(incl, off);
      if (lane >= off) incl += t;
    }
    if (lane == 63) wbase[w] = incl;
    __syncthreads();
    if (w == 0) {
      int t = (lane < 16) ? wbase[lane] : 0;
      int it = t;
#pragma unroll
      for (int off = 1; off < 16; off <<= 1) {
        int v2 = __shfl_up(it, off);
        if (lane >= off) it += v2;
      }
      if (lane < 16) wbase[lane] = it - t;
      if (lane == 15) chunk_tot = it;
    }
    __syncthreads();
    int run = carry + wbase[w] + (incl - x);
#pragma unroll
    for (int j = 0; j < 4; j++) {
      if (i0 + j < n) {
        out[i0 + j] = run;
        if (cur) cur[i0 + j] = run;
      }
      run += v[j];
    }
    carry += chunk_tot;
    __syncthreads();
  }
  if (tid == 0) out[n] = carry;
}

__global__ void k_scatter(const int* __restrict__ src, const int* __restrict__ dst, int n,
                          int* __restrict__ cursor, int* __restrict__ dst_sorted) {
  int e = blockIdx.x * blockDim.x + threadIdx.x;
  if (e < n) {
    int s = src[e];
    int slot = atomicAdd(&cursor[s], 1);
    dst_sorted[slot] = dst[e];
  }
}

__global__ void k_gptr(const int* __restrict__ batch, int* __restrict__ gptr) {
  int g = blockIdx.x * blockDim.x + threadIdx.x;
  if (g > GG) return;
  int lo = 0, hi = NN;
  while (lo < hi) {
    int mid = (lo + hi) >> 1;
    if (batch[mid] < g) lo = mid + 1; else hi = mid;
  }
  gptr[g] = lo;
}

// Sort each node's dst list ascending (perf-only: edge order is semantically
// irrelevant; sorted lists make concurrent waves sweep the gather array in
// phase -> L2-resident hot front). Wave-per-node odd-even transposition sort
// over 64 lanes; nodes with degree > 64 left unsorted (rare, still correct).
__global__ __launch_bounds__(256) void k_sortrows(const int* __restrict__ rowp,
                                                  int* __restrict__ dsts, int n) {
  int node = blockIdx.x * 4 + (threadIdx.x >> 6);
  int lane = threadIdx.x & 63;
  if (node >= n) return;
  int e0 = rowp[node], e1 = rowp[node + 1];
  int deg = e1 - e0;
  if (deg <= 1 || deg > 64) return;
  int v = (lane < deg) ? dsts[e0 + lane] : 0x7fffffff;
#pragma unroll
  for (int r = 0; r < 64; r++) {
    int s = r & 1;
    int rel = lane - s;
    int partner = (rel ^ 1) + s;
    bool valid = (rel >= 0) && (partner >= 0) && (partner < 64);
    int q = __shfl(v, valid ? partner : lane);
    bool lowhalf = (rel & 1) == 0;
    int vmin = min(v, q), vmax = max(v, q);
    if (valid) v = lowhalf ? vmin : vmax;
  }
  if (lane < deg) dsts[e0 + lane] = v;
}

// ---------------- MFMA building blocks ----------------
union AB {
  short8 v;
  u32 w[4];
};

__device__ __forceinline__ void build_hl(const float* xv, AB& ah, AB& al) {
#pragma unroll
  for (int p = 0; p < 4; p++) {
    u32 h0 = bf16r(xv[2 * p]), h1 = bf16r(xv[2 * p + 1]);
    float f0 = __uint_as_float(h0 << 16), f1 = __uint_as_float(h1 << 16);
    ah.w[p] = h0 | (h1 << 16);
    al.w[p] = bf16r(xv[2 * p] - f0) | (bf16r(xv[2 * p + 1] - f1) << 16);
  }
}

__device__ __forceinline__ void mfma3(const AB& ah, const AB& al, const u16* __restrict__ Wh,
                                      const u16* __restrict__ Wl, int q, int lane, f32x4* acc) {
  const u16* bph = Wh + ((size_t)(q * 8) * 64 + lane) * 8;
  const u16* bpl = Wl + ((size_t)(q * 8) * 64 + lane) * 8;
#pragma unroll
  for (int t = 0; t < 8; t++) {
    short8 bh = *(const short8*)(bph + t * 512);
    short8 bl = *(const short8*)(bpl + t * 512);
    acc[t] = __builtin_amdgcn_mfma_f32_16x16x32_bf16(ah.v, bh, acc[t], 0, 0, 0);
    acc[t] = __builtin_amdgcn_mfma_f32_16x16x32_bf16(al.v, bh, acc[t], 0, 0, 0);
    acc[t] = __builtin_amdgcn_mfma_f32_16x16x32_bf16(ah.v, bl, acc[t], 0, 0, 0);
  }
}

__device__ __forceinline__ void gemm_packhl(const u32* __restrict__ A32, int mld,
                                            const u16* __restrict__ Wh,
                                            const u16* __restrict__ Wl, int lane, int quad,
                                            f32x4* acc) {
#pragma unroll
  for (int q = 0; q < 4; q++) {
    int k0 = q * 32 + quad * 8;
    const u32* ap = A32 + (size_t)mld * 128 + k0;
    uint4 u0 = *(const uint4*)ap;
    uint4 u1 = *(const uint4*)(ap + 4);
    u32 uu[8] = {u0.x, u0.y, u0.z, u0.w, u1.x, u1.y, u1.z, u1.w};
    AB ah, al;
#pragma unroll
    for (int p = 0; p < 4; p++) {
      ah.w[p] = __builtin_amdgcn_perm(uu[2 * p + 1], uu[2 * p], 0x05040100u);
      al.w[p] = __builtin_amdgcn_perm(uu[2 * p + 1], uu[2 * p], 0x07060302u);
    }
    mfma3(ah, al, Wh, Wl, q, lane, acc);
  }
}

__device__ __forceinline__ void gemm_lds(const float (*tile)[129], int ml, int quad, int lane,
                                         const u16* __restrict__ Wh, const u16* __restrict__ Wl,
                                         f32x4* acc) {
#pragma unroll
  for (int q = 0; q < 4; q++) {
    int k0 = q * 32 + quad * 8;
    float xv[8];
#pragma unroll
    for (int j = 0; j < 8; j++) xv[j] = tile[ml][k0 + j];
    AB ah, al;
    build_hl(xv, ah, al);
    mfma3(ah, al, Wh, Wl, q, lane, acc);
  }
}

__device__ __forceinline__ void bias8(const float* __restrict__ bias, int ml, float* bj) {
#pragma unroll
  for (int t = 0; t < 8; t++) {
    int col = t * 16 + ml;
    bj[t] = (bias != nullptr && col < DD) ? bias[col] : 0.f;
  }
}

template <int TANH>
__device__ __forceinline__ void row_vs(const f32x4* acc, const float* bj, int r, float* vs) {
#pragma unroll
  for (int t = 0; t < 8; t++) {
    float v = acc[t][r] + bj[t];
    if (TANH) {
      float e = exp2f(v * 2.8853900817779268f);  // exp(2v)
      v = 1.f - 2.f / (e + 1.f);
    }
    vs[t] = v;
  }
}

__device__ __forceinline__ void store_T_row(const float* vs, u32* __restrict__ To, int rowD,
                                            int ml) {
  u32* to = To + (size_t)rowD * 128 + ml;
#pragma unroll
  for (int t = 0; t < 8; t++) to[t * 16] = packhl(vs[t]);
}

// point store: slot s=t*16+ml holds half2(spatial col s, col s+64); time -> Pt[rowD*2]
__device__ __forceinline__ void store_P_row(const float* vs, u32* __restrict__ Pb,
                                            float* __restrict__ Pt, int rowD, int ml, float cc,
                                            float sc, float pscale) {
  float ps = 0.f;
#pragma unroll
  for (int t = 0; t < 8; t++) ps += vs[t] * vs[t];
#pragma unroll
  for (int off = 1; off < 16; off <<= 1) ps += __shfl_xor(ps, off);
  float nn = fmaxf(sqrtf(ps), 1e-9f);
  float e = expf(nn / sc);
  float f = sc * (e - 1.f / e) * 0.5f / nn;  // sc*sinh(nn/sc)/nn
  float tt = sqrtf(cc + f * f * ps);
  f *= pscale;
  u32* pb = Pb + (size_t)rowD * 128 + ml;
#pragma unroll
  for (int t = 0; t < 4; t++) pb[t * 16] = pk2h(f * vs[t], f * vs[t + 4]);
  if (ml == 0) Pt[rowD * 2] = pscale * tt;
}

// ---------------- fused input GEMM + att-GEMM(layer0) ----------------
__global__ __launch_bounds__(256) void k_gemm_in(
    const float* __restrict__ x, const u16* __restrict__ WhI, const u16* __restrict__ WlI,
    const u16* __restrict__ WhA, const u16* __restrict__ WlA, const float* __restrict__ attb,
    u32* __restrict__ To, u32* __restrict__ HHh, float* __restrict__ ptF,
    const float* __restrict__ cptr, int M) {
  __shared__ float tile[4][16][129];
  int lane = threadIdx.x & 63, wid = threadIdx.x >> 6;
  int m0 = blockIdx.x * 64 + wid * 16;
  int ml = lane & 15, quad = lane >> 4;
  int mld = m0 + ml;
  f32x4 acc[8];
#pragma unroll
  for (int t = 0; t < 8; t++) acc[t] = (f32x4){0.f, 0.f, 0.f, 0.f};
#pragma unroll
  for (int q = 0; q < 7; q++) {
    int k0 = q * 32 + quad * 8;
    bool ok = (mld < M) && (k0 + 7 < IN_F);
    const float* ap = x + (size_t)mld * IN_F + k0;
    float4 x0 = ok ? *(const float4*)ap : make_float4(0.f, 0.f, 0.f, 0.f);
    float4 x1 = ok ? *(const float4*)(ap + 4) : make_float4(0.f, 0.f, 0.f, 0.f);
    float xv[8] = {x0.x, x0.y, x0.z, x0.w, x1.x, x1.y, x1.z, x1.w};
    AB ah, al;
    build_hl(xv, ah, al);
    mfma3(ah, al, WhI, WlI, q, lane, acc);
  }
  float cc = *cptr, sc = sqrtf(cc);
  {
    float bj[8];
    bias8(nullptr, ml, bj);
#pragma unroll
    for (int r = 0; r < 4; r++) {
      int rowD = m0 + quad * 4 + r;
      float vs[8];
      row_vs<0>(acc, bj, r, vs);
      if (rowD < M) {
        store_T_row(vs, To, rowD, ml);
        store_P_row(vs, HHh + 64, ptF + 1, rowD, ml, cc, sc, PS_SCALE);
      }
#pragma unroll
      for (int t = 0; t < 8; t++) tile[wid][quad * 4 + r][t * 16 + ml] = vs[t];
    }
  }
#pragma unroll
  for (int t = 0; t < 8; t++) acc[t] = (f32x4){0.f, 0.f, 0.f, 0.f};
  gemm_lds(tile[wid], ml, quad, lane, WhA, WlA, acc);
  {
    float bj[8];
    bias8(attb, ml, bj);
#pragma unroll
    for (int r = 0; r < 4; r++) {
      int rowD = m0 + quad * 4 + r;
      float vs[8];
      row_vs<0>(acc, bj, r, vs);
      if (rowD < M) store_P_row(vs, HHh, ptF, rowD, ml, cc, sc, 1.f);
    }
  }
}

// ---------------- fused MLP pair (+ next layer's att GEMM unless LAST) ----------------
template <int LAST>
__global__ __launch_bounds__(256) void k_mlp3(
    const u32* __restrict__ A32, const u16* __restrict__ Wha, const u16* __restrict__ Wla,
    const float* __restrict__ ba, const u16* __restrict__ Whb, const u16* __restrict__ Wlb,
    const float* __restrict__ bb, const u16* __restrict__ WhA, const u16* __restrict__ WlA,
    const float* __restrict__ attb, u32* __restrict__ To, u32* __restrict__ HHh,
    float* __restrict__ ptF, const float* __restrict__ cptr, int M) {
  __shared__ float tile[4][16][129];
  int lane = threadIdx.x & 63, wid = threadIdx.x >> 6;
  int m0 = blockIdx.x * 64 + wid * 16;
  int ml = lane & 15, quad = lane >> 4;
  int mld = m0 + ml;
  f32x4 acc[8];
#pragma unroll
  for (int t = 0; t < 8; t++) acc[t] = (f32x4){0.f, 0.f, 0.f, 0.f};
  gemm_packhl(A32, mld, Wha, Wla, lane, quad, acc);
  {
    float bj[8];
    bias8(ba, ml, bj);
#pragma unroll
    for (int r = 0; r < 4; r++) {
      float vs[8];
      row_vs<1>(acc, bj, r, vs);
#pragma unroll
      for (int t = 0; t < 8; t++) tile[wid][quad * 4 + r][t * 16 + ml] = vs[t];
    }
  }
#pragma unroll
  for (int t = 0; t < 8; t++) acc[t] = (f32x4){0.f, 0.f, 0.f, 0.f};
  gemm_lds(tile[wid], ml, quad, lane, Whb, Wlb, acc);
  float cc = 1.f, sc = 1.f;
  if (!LAST) {
    cc = *cptr;
    sc = sqrtf(cc);
  }
  {
    float bj[8];
    bias8(bb, ml, bj);
#pragma unroll
    for (int r = 0; r < 4; r++) {
      int rowD = m0 + quad * 4 + r;
      float vs[8];
      row_vs<1>(acc, bj, r, vs);
      if (rowD < M) store_T_row(vs, To, rowD, ml);
      if (!LAST) {
        if (rowD < M) store_P_row(vs, HHh + 64, ptF + 1, rowD, ml, cc, sc, PS_SCALE);
#pragma unroll
        for (int t = 0; t < 8; t++) tile[wid][quad * 4 + r][t * 16 + ml] = vs[t];
      }
    }
  }
  if (!LAST) {
#pragma unroll
    for (int t = 0; t < 8; t++) acc[t] = (f32x4){0.f, 0.f, 0.f, 0.f};
    gemm_lds(tile[wid], ml, quad, lane, WhA, WlA, acc);
    float bj[8];
    bias8(attb, ml, bj);
#pragma unroll
    for (int r = 0; r < 4; r++) {
      int rowD = m0 + quad * 4 + r;
      float vs[8];
      row_vs<0>(acc, bj, r, vs);
      if (rowD < M) store_P_row(vs, HHh, ptF, rowD, ml, cc, sc, 1.f);
    }
  }
}

// ---------------- fused attention + aggregation, 8-lane edge groups ----------------
// HHh row (128 u32): [0..63] HL half2 (cols s, s+64); [64..127] H half2 * 2^-6.
// ptHH[node] = (time(HL), time(H)*2^-6).
__global__ __launch_bounds__(256) void k_agg_o(const u32* __restrict__ HHh,
                                               const float2* __restrict__ ptHH,
                                               const u32* __restrict__ T,
                                               const int* __restrict__ rowp,
                                               const int* __restrict__ dsts,
                                               const float* __restrict__ epsp,
                                               const float* __restrict__ cptr,
                                               u32* __restrict__ Tout, int n) {
  int node = blockIdx.x * 4 + (threadIdx.x >> 6);
  int lane = threadIdx.x & 63;
  if (node >= n) return;
  int o = lane & 7, g = lane >> 3;
  float c = *cptr, sc = sqrtf(c), rcpc = 1.f / c;
  float eps = *epsp;
  const u32* arow = HHh + (size_t)node * 128 + o * 8;
  uint4 a0 = *(const uint4*)arow;
  uint4 a1 = *(const uint4*)(arow + 4);
  u32 apk[8] = {a0.x, a0.y, a0.z, a0.w, a1.x, a1.y, a1.z, a1.w};
  float pts = ptHH[node].x;
  int e0 = rowp[node], e1 = rowp[node + 1];
  int iters = (e1 - e0 + 7) >> 3;
  h2f mpk[8];
  {
    UH z;
    z.u = 0;
#pragma unroll
    for (int j = 0; j < 8; j++) mpk[j] = z.h;
  }
  float mt = 0.f;
#pragma unroll 2
  for (int it = 0; it < iters; it++) {
    int e = e0 + it * 8 + g;
    bool ve = e < e1;
    int d = dsts[ve ? e : e0];
    const u32* rb = HHh + (size_t)d * 128 + o * 8;
    uint4 b0 = *(const uint4*)rb;
    uint4 b1 = *(const uint4*)(rb + 4);
    uint4 h0 = *(const uint4*)(rb + 64);
    uint4 h1 = *(const uint4*)(rb + 68);
    float2 pp = ptHH[d];
    u32 bw[8] = {b0.x, b0.y, b0.z, b0.w, b1.x, b1.y, b1.z, b1.w};
    float dot = 0.f;
#pragma unroll
    for (int j = 0; j < 8; j++) dot = fdot2h(apk[j], bw[j], dot);
    dot += __shfl_xor(dot, 1);
    dot += __shfl_xor(dot, 2);
    dot += __shfl_xor(dot, 4);
    float valv = fmaxf((pts * pp.x - dot) * rcpc, 1.f + EPSH);
    float w = valv + sqrtf(fmaf(valv, valv, -1.f));
    float att = exp2f(-sc * __log2f(w));  // exp(-sc*acosh(val))
    att = ve ? att : 0.f;
    UH att2;
    att2.u = pk2h(att, att);
    u32 hw[8] = {h0.x, h0.y, h0.z, h0.w, h1.x, h1.y, h1.z, h1.w};
#pragma unroll
    for (int j = 0; j < 8; j++) {
      UH hv;
      hv.u = hw[j];
      mpk[j] = att2.h * hv.h + mpk[j];  // v_pk_fma_f16
    }
    mt = fmaf(att, pp.y, mt);
  }
  // cross-group reduce (offsets 8,16,32)
#pragma unroll
  for (int off = 8; off <= 32; off <<= 1) {
#pragma unroll
    for (int j = 0; j < 8; j++) {
      UH v;
      v.h = mpk[j];
      UH s;
      s.u = (u32)__shfl_xor((int)v.u, off);
      mpk[j] = v.h + s.h;
    }
    mt += __shfl_xor(mt, off);
  }
  // lsq over the full spatial vector (slots partitioned across o; reduce 1,2,4)
  float lp = 0.f;
#pragma unroll
  for (int j = 0; j < 8; j++) {
    float lo = (float)mpk[j][0], hi = (float)mpk[j][1];
    lp = fmaf(lo, lo, lp);
    lp = fmaf(hi, hi, lp);
  }
  lp += __shfl_xor(lp, 1);
  lp += __shfl_xor(lp, 2);
  lp += __shfl_xor(lp, 4);
  float lsq = lp;
  float neg_inner = mt * mt - lsq;
  float denom = sqrtf(fmaxf(neg_inner, 1e-9f));
  float r = sc / denom;
  float ssq = r * r * lsq;
  float agg0 = sqrtf(c + ssq);
  float ynA = fmaxf(sqrtf(ssq), 1e-9f);
  float v2 = fmaxf(agg0 / sc, 1.f + EPSH);
  float dA = sc * 0.69314718056f * __log2f(v2 + sqrtf(v2 * v2 - 1.f));
  float sca = dA * r / ynA;
  if (g == 0) {
    const u32* tp = T + (size_t)node * 128 + o * 8;
    uint4 t0 = *(const uint4*)tp;
    uint4 t0b = *(const uint4*)(tp + 4);
    uint4 t1 = *(const uint4*)(tp + 64);
    uint4 t1b = *(const uint4*)(tp + 68);
    u32 tw[8] = {t0.x, t0.y, t0.z, t0.w, t0b.x, t0b.y, t0b.z, t0b.w};
    u32 tv[8] = {t1.x, t1.y, t1.z, t1.w, t1b.x, t1b.y, t1b.z, t1b.w};
    float oe = 1.f + eps;
    u32 olo[8], ohi[8];
#pragma unroll
    for (int j = 0; j < 8; j++) {
      float lo = (float)mpk[j][0], hi = (float)mpk[j][1];
      olo[j] = packhl(fmaf(sca, lo, oe * rec(tw[j])));
      ohi[j] = packhl(fmaf(sca, hi, oe * rec(tv[j])));
    }
    u32* op = Tout + (size_t)node * 128 + o * 8;
    *(uint4*)op = make_uint4(olo[0], olo[1], olo[2], olo[3]);
    *(uint4*)(op + 4) = make_uint4(olo[4], olo[5], olo[6], olo[7]);
    *(uint4*)(op + 64) = make_uint4(ohi[0], ohi[1], ohi[2], ohi[3]);
    *(uint4*)(op + 68) = make_uint4(ohi[4], ohi[5], ohi[6], ohi[7]);
  }
}

// ---------------- pooling ----------------
__global__ void k_pool(const u32* __restrict__ U, const int* __restrict__ gptr,
                       float* __restrict__ out, int layer) {
  int g = blockIdx.x;
  int c = threadIdx.x;  // 0..127
  int s = gptr[g], e = gptr[g + 1];
  float acc = 0.f;
  if (c > 0) {
    const u32* up = U + (c - 1);
    int i = s;
    float a0 = 0.f, a1 = 0.f, a2 = 0.f, a3 = 0.f;
    for (; i + 3 < e; i += 4) {
      a0 += rec(up[(size_t)i * 128]);
      a1 += rec(up[(size_t)(i + 1) * 128]);
      a2 += rec(up[(size_t)(i + 2) * 128]);
      a3 += rec(up[(size_t)(i + 3) * 128]);
    }
    for (; i < e; i++) a0 += rec(up[(size_t)i * 128]);
    acc = (a0 + a1) + (a2 + a3);
  }
  out[(size_t)g * 256 + layer * 128 + c] = acc;
}

// ---------------- launch ----------------
extern "C" void kernel_launch(void* const* d_in, const int* in_sizes, int n_in, void* d_out,
                              int out_size, void* d_ws, size_t ws_size, hipStream_t stream) {
  const float* x = (const float*)d_in[0];
  const float* cptr = (const float*)d_in[1];
  const float* w_in = (const float*)d_in[2];
  const float* att_w = (const float*)d_in[3];
  const float* att_b = (const float*)d_in[4];
  const float* epsv = (const float*)d_in[5];
  const float* mlp_w = (const float*)d_in[6];
  const float* mlp_b = (const float*)d_in[7];
  const int* ei = (const int*)d_in[8];
  const int* batch = (const int*)d_in[9];
  const int* srcp = ei;
  const int* dstp = ei + EE;
  float* out = (float*)d_out;

  u32* ws = (u32*)d_ws;
  u16* Wfh = (u16*)ws;  // WF_TOT u16
  u16* Wfl = Wfh + WF_TOT;
  int* deg = (int*)(ws + 126976);  // N
  int* rowp = deg + NN;            // N+1
  int* cursor = rowp + NN + 1;     // N
  int* gptr = cursor + NN;         // G+1
  int* dsts = gptr + GG + 1;       // E
  size_t o1 = (size_t)((u32*)(dsts + EE) - ws);
  o1 = (o1 + 3) & ~(size_t)3;
  float2* ptHH = (float2*)(ws + o1);   // NNP float2
  u32* HHh = ws + o1 + 2 * NNP;        // NNP*128 (HL | H), half2 slots
  u32* A32 = HHh + (size_t)NNP * 128;  // NNP*128 packhl tangent
  u32* B32 = A32 + (size_t)NNP * 128;  // NNP*128

  const int EW = 12500;  // agg/sort: 4 nodes/block
  const int GEMMG = (NN + 63) / 64;
  float* ptF = (float*)ptHH;

  (void)hipMemsetAsync(deg, 0, NN * sizeof(int), stream);
  k_prep_wf<<<64, 256, 0, stream>>>(att_w, mlp_w, w_in, Wfh, Wfl);
  k_count<<<(EE + 255) / 256, 256, 0, stream>>>(srcp, EE, deg);
  k_gptr<<<3, 256, 0, stream>>>(batch, gptr);
  k_scan_excl<<<1, 1024, 0, stream>>>(deg, NN, rowp, cursor);
  k_scatter<<<(EE + 255) / 256, 256, 0, stream>>>(srcp, dstp, EE, cursor, dsts);
  k_sortrows<<<EW, 256, 0, stream>>>(rowp, dsts, NN);

#define WH(m) (Wfh + 28672 + (m) * 16384)
#define WL(m) (Wfl + 28672 + (m) * 16384)

  // input GEMM + att0: T0 -> A32 ; H0 -> (HHh+64, ptF odd) ; HL0 -> (HHh, ptF even)
  k_gemm_in<<<GEMMG, 256, 0, stream>>>(x, Wfh, Wfl, WH(0), WL(0), att_b, A32, HHh, ptF, cptr, NN);

  // ---- layer 0 ----
  k_agg_o<<<EW, 256, 0, stream>>>(HHh, ptHH, A32, rowp, dsts, epsv + 0, cptr, B32, NN);
  k_mlp3<0><<<GEMMG, 256, 0, stream>>>(B32, WH(2), WL(2), mlp_b + 0 * DD, WH(3), WL(3),
                                       mlp_b + 1 * DD, WH(1), WL(1), att_b + DD, A32, HHh, ptF,
                                       cptr, NN);
  k_pool<<<GG, 128, 0, stream>>>(A32, gptr, out, 0);

  // ---- layer 1 ----
  k_agg_o<<<EW, 256, 0, stream>>>(HHh, ptHH, A32, rowp, dsts, epsv + 1, cptr, B32, NN);
  k_mlp3<1><<<GEMMG, 256, 0, stream>>>(B32, WH(4), WL(4), mlp_b + 2 * DD, WH(5), WL(5),
                                       mlp_b + 3 * DD, nullptr, nullptr, nullptr, B32, nullptr,
                                       nullptr, cptr, NN);
  k_pool<<<GG, 128, 0, stream>>>(B32, gptr, out, 1);
}

// Round 11
// 508.505 us; speedup vs baseline: 1.2246x; 1.0936x over previous
//
#include <hip/hip_runtime.h>
#include <hip/hip_fp16.h>
#include <math.h>

#define NN 50000
#define NNP 50048
#define EE 800000
#define IN_F 200
#define DD 127
#define GG 512
#define EPSH 1e-5f
#define PS_SCALE 0.015625f  // 2^-6 pre-scale on H points (centroid is scale-invariant)

typedef unsigned int u32;
typedef unsigned short u16;
typedef __attribute__((ext_vector_type(8))) short short8;
typedef __attribute__((ext_vector_type(4))) float f32x4;
typedef _Float16 h2f __attribute__((ext_vector_type(2)));
typedef __fp16 fp16x2 __attribute__((ext_vector_type(2)));
union UH {
  u32 u;
  h2f h;
  fp16x2 f;
};

__device__ __forceinline__ u32 bf16r(float x) {
  u32 u = __float_as_uint(x);
  return (u + 0x7fffu + ((u >> 16) & 1u)) >> 16;
}

__device__ __forceinline__ u32 packhl(float v) {  // u32 = bf16_hi | bf16_lo<<16
  u32 hi = bf16r(v);
  float vh = __uint_as_float(hi << 16);
  u32 lo = bf16r(v - vh);
  return hi | (lo << 16);
}

__device__ __forceinline__ float rec(u32 u) {
  return __uint_as_float(u << 16) + __uint_as_float(u & 0xffff0000u);
}

__device__ __forceinline__ u32 pk2h(float a, float b) {  // packed half2 bits
#if __has_builtin(__builtin_amdgcn_cvt_pkrtz)
  UH x;
  x.f = __builtin_amdgcn_cvt_pkrtz(a, b);
  return x.u;
#else
  __half2 r = __floats2half2_rn(a, b);
  return *(u32*)&r;
#endif
}

__device__ __forceinline__ float fdot2h(u32 a, u32 b, float acc) {
  UH ua, ub;
  ua.u = a;
  ub.u = b;
#if __has_builtin(__builtin_amdgcn_fdot2)
  return __builtin_amdgcn_fdot2(ua.h, ub.h, acc, false);
#else
  acc = fmaf((float)ua.h[0], (float)ub.h[0], acc);
  return fmaf((float)ua.h[1], (float)ub.h[1], acc);
#endif
}

__device__ __forceinline__ float frcp(float x) {
#if __has_builtin(__builtin_amdgcn_rcpf)
  return __builtin_amdgcn_rcpf(x);
#else
  return 1.f / x;
#endif
}

// ---------------- merged setup: weights->frags | gptr | degree count ----------------
#define WF_TOT (28672 + 6 * 16384)
#define SETUP_PREP_BLKS 64
#define SETUP_GPTR_BLKS 3
__global__ void k_setup(const float* __restrict__ att_w, const float* __restrict__ mlp_w,
                        const float* __restrict__ w_in, u16* __restrict__ Wfh,
                        u16* __restrict__ Wfl, const int* __restrict__ batch,
                        int* __restrict__ gptr, const int* __restrict__ srcp,
                        int* __restrict__ deg) {
  int b = blockIdx.x, tid = threadIdx.x;
  if (b < SETUP_PREP_BLKS) {
    for (int idx = b * 256 + tid; idx < WF_TOT; idx += SETUP_PREP_BLKS * 256) {
      float val;
      if (idx < 28672) {
        int q = idx >> 12, rem = idx & 4095;
        int t = rem >> 9, l = (rem >> 3) & 63, j = rem & 7;
        int k = q * 32 + ((l >> 4) << 3) + j, n = t * 16 + (l & 15);
        val = (k < IN_F && n < DD) ? w_in[k * DD + n] : 0.f;
      } else {
        int rel = idx - 28672;
        int mat = rel >> 14, rem = rel & 16383;
        int q = rem >> 12;
        rem &= 4095;
        int t = rem >> 9, l = (rem >> 3) & 63, j = rem & 7;
        int k = q * 32 + ((l >> 4) << 3) + j, n = t * 16 + (l & 15);
        const float* wsrc = (mat < 2) ? att_w + mat * DD * DD : mlp_w + (mat - 2) * DD * DD;
        val = (k < DD && n < DD) ? wsrc[n * DD + k] : 0.f;
      }
      u32 hi = bf16r(val);
      float vh = __uint_as_float(hi << 16);
      u32 lo = bf16r(val - vh);
      Wfh[idx] = (u16)hi;
      Wfl[idx] = (u16)lo;
    }
  } else if (b < SETUP_PREP_BLKS + SETUP_GPTR_BLKS) {
    int g = (b - SETUP_PREP_BLKS) * 256 + tid;
    if (g <= GG) {
      int lo = 0, hi = NN;
      while (lo < hi) {
        int mid = (lo + hi) >> 1;
        if (batch[mid] < g) lo = mid + 1; else hi = mid;
      }
      gptr[g] = lo;
    }
  } else {
    int i = (b - SETUP_PREP_BLKS - SETUP_GPTR_BLKS) * 256 + tid;
    if (i < EE) atomicAdd(&deg[srcp[i]], 1);
  }
}

// ---------------- CSR build ----------------
__global__ __launch_bounds__(1024) void k_scan_excl(const int* __restrict__ in, int n,
                                                    int* __restrict__ out, int* __restrict__ cur) {
  __shared__ int wbase[16];
  __shared__ int chunk_tot;
  int tid = threadIdx.x;
  int lane = tid & 63;
  int w = tid >> 6;
  int carry = 0;
  for (int base = 0; base < n; base += 4096) {
    int i0 = base + tid * 4;
    int v[4];
#pragma unroll
    for (int j = 0; j < 4; j++) v[j] = (i0 + j < n) ? in[i0 + j] : 0;
    int x = v[0] + v[1] + v[2] + v[3];
    int incl = x;
#pragma unroll
    for (int off = 1; off < 64; off <<= 1) {
      int t = __shfl_up(incl, off);
      if (lane >= off) incl += t;
    }
    if (lane == 63) wbase[w] = incl;
    __syncthreads();
    if (w == 0) {
      int t = (lane < 16) ? wbase[lane] : 0;
      int it = t;
#pragma unroll
      for (int off = 1; off < 16; off <<= 1) {
        int v2 = __shfl_up(it, off);
        if (lane >= off) it += v2;
      }
      if (lane < 16) wbase[lane] = it - t;
      if (lane == 15) chunk_tot = it;
    }
    __syncthreads();
    int run = carry + wbase[w] + (incl - x);
#pragma unroll
    for (int j = 0; j < 4; j++) {
      if (i0 + j < n) {
        out[i0 + j] = run;
        if (cur) cur[i0 + j] = run;
      }
      run += v[j];
    }
    carry += chunk_tot;
    __syncthreads();
  }
  if (tid == 0) out[n] = carry;
}

__global__ void k_scatter(const int* __restrict__ src, const int* __restrict__ dst, int n,
                          int* __restrict__ cursor, int* __restrict__ dst_sorted) {
  int e = blockIdx.x * blockDim.x + threadIdx.x;
  if (e < n) {
    int s = src[e];
    int slot = atomicAdd(&cursor[s], 1);
    dst_sorted[slot] = dst[e];
  }
}

// ---------------- MFMA building blocks ----------------
union AB {
  short8 v;
  u32 w[4];
};

__device__ __forceinline__ void build_hl(const float* xv, AB& ah, AB& al) {
#pragma unroll
  for (int p = 0; p < 4; p++) {
    u32 h0 = bf16r(xv[2 * p]), h1 = bf16r(xv[2 * p + 1]);
    float f0 = __uint_as_float(h0 << 16), f1 = __uint_as_float(h1 << 16);
    ah.w[p] = h0 | (h1 << 16);
    al.w[p] = bf16r(xv[2 * p] - f0) | (bf16r(xv[2 * p + 1] - f1) << 16);
  }
}

__device__ __forceinline__ void mfma3(const AB& ah, const AB& al, const u16* __restrict__ Wh,
                                      const u16* __restrict__ Wl, int q, int lane, f32x4* acc) {
  const u16* bph = Wh + ((size_t)(q * 8) * 64 + lane) * 8;
  const u16* bpl = Wl + ((size_t)(q * 8) * 64 + lane) * 8;
#pragma unroll
  for (int t = 0; t < 8; t++) {
    short8 bh = *(const short8*)(bph + t * 512);
    short8 bl = *(const short8*)(bpl + t * 512);
    acc[t] = __builtin_amdgcn_mfma_f32_16x16x32_bf16(ah.v, bh, acc[t], 0, 0, 0);
    acc[t] = __builtin_amdgcn_mfma_f32_16x16x32_bf16(al.v, bh, acc[t], 0, 0, 0);
    acc[t] = __builtin_amdgcn_mfma_f32_16x16x32_bf16(ah.v, bl, acc[t], 0, 0, 0);
  }
}

__device__ __forceinline__ void gemm_packhl(const u32* __restrict__ A32, int mld,
                                            const u16* __restrict__ Wh,
                                            const u16* __restrict__ Wl, int lane, int quad,
                                            f32x4* acc) {
#pragma unroll
  for (int q = 0; q < 4; q++) {
    int k0 = q * 32 + quad * 8;
    const u32* ap = A32 + (size_t)mld * 128 + k0;
    uint4 u0 = *(const uint4*)ap;
    uint4 u1 = *(const uint4*)(ap + 4);
    u32 uu[8] = {u0.x, u0.y, u0.z, u0.w, u1.x, u1.y, u1.z, u1.w};
    AB ah, al;
#pragma unroll
    for (int p = 0; p < 4; p++) {
      ah.w[p] = __builtin_amdgcn_perm(uu[2 * p + 1], uu[2 * p], 0x05040100u);
      al.w[p] = __builtin_amdgcn_perm(uu[2 * p + 1], uu[2 * p], 0x07060302u);
    }
    mfma3(ah, al, Wh, Wl, q, lane, acc);
  }
}

__device__ __forceinline__ void gemm_lds(const float (*tile)[129], int ml, int quad, int lane,
                                         const u16* __restrict__ Wh, const u16* __restrict__ Wl,
                                         f32x4* acc) {
#pragma unroll
  for (int q = 0; q < 4; q++) {
    int k0 = q * 32 + quad * 8;
    float xv[8];
#pragma unroll
    for (int j = 0; j < 8; j++) xv[j] = tile[ml][k0 + j];
    AB ah, al;
    build_hl(xv, ah, al);
    mfma3(ah, al, Wh, Wl, q, lane, acc);
  }
}

__device__ __forceinline__ void bias8(const float* __restrict__ bias, int ml, float* bj) {
#pragma unroll
  for (int t = 0; t < 8; t++) {
    int col = t * 16 + ml;
    bj[t] = (bias != nullptr && col < DD) ? bias[col] : 0.f;
  }
}

template <int TANH>
__device__ __forceinline__ void row_vs(const f32x4* acc, const float* bj, int r, float* vs) {
#pragma unroll
  for (int t = 0; t < 8; t++) {
    float v = acc[t][r] + bj[t];
    if (TANH) {
      float e = exp2f(v * 2.8853900817779268f);  // exp(2v)
      v = 1.f - 2.f / (e + 1.f);
    }
    vs[t] = v;
  }
}

__device__ __forceinline__ void store_T_row(const float* vs, u32* __restrict__ To, int rowD,
                                            int ml) {
  u32* to = To + (size_t)rowD * 128 + ml;
#pragma unroll
  for (int t = 0; t < 8; t++) to[t * 16] = packhl(vs[t]);
}

// point store: slot s=t*16+ml holds half2(spatial col s, col s+64); time -> Pt[rowD*2]
__device__ __forceinline__ void store_P_row(const float* vs, u32* __restrict__ Pb,
                                            float* __restrict__ Pt, int rowD, int ml, float cc,
                                            float sc, float pscale) {
  float ps = 0.f;
#pragma unroll
  for (int t = 0; t < 8; t++) ps += vs[t] * vs[t];
#pragma unroll
  for (int off = 1; off < 16; off <<= 1) ps += __shfl_xor(ps, off);
  float nn = fmaxf(sqrtf(ps), 1e-9f);
  float e = expf(nn / sc);
  float f = sc * (e - 1.f / e) * 0.5f / nn;  // sc*sinh(nn/sc)/nn
  float tt = sqrtf(cc + f * f * ps);
  f *= pscale;
  u32* pb = Pb + (size_t)rowD * 128 + ml;
#pragma unroll
  for (int t = 0; t < 4; t++) pb[t * 16] = pk2h(f * vs[t], f * vs[t + 4]);
  if (ml == 0) Pt[rowD * 2] = pscale * tt;
}

// ---------------- fused input GEMM + att-GEMM(layer0) ----------------
__global__ __launch_bounds__(256) void k_gemm_in(
    const float* __restrict__ x, const u16* __restrict__ WhI, const u16* __restrict__ WlI,
    const u16* __restrict__ WhA, const u16* __restrict__ WlA, const float* __restrict__ attb,
    u32* __restrict__ To, u32* __restrict__ HHh, float* __restrict__ ptF,
    const float* __restrict__ cptr, int M) {
  __shared__ float tile[4][16][129];
  int lane = threadIdx.x & 63, wid = threadIdx.x >> 6;
  int m0 = blockIdx.x * 64 + wid * 16;
  int ml = lane & 15, quad = lane >> 4;
  int mld = m0 + ml;
  f32x4 acc[8];
#pragma unroll
  for (int t = 0; t < 8; t++) acc[t] = (f32x4){0.f, 0.f, 0.f, 0.f};
#pragma unroll
  for (int q = 0; q < 7; q++) {
    int k0 = q * 32 + quad * 8;
    bool ok = (mld < M) && (k0 + 7 < IN_F);
    const float* ap = x + (size_t)mld * IN_F + k0;
    float4 x0 = ok ? *(const float4*)ap : make_float4(0.f, 0.f, 0.f, 0.f);
    float4 x1 = ok ? *(const float4*)(ap + 4) : make_float4(0.f, 0.f, 0.f, 0.f);
    float xv[8] = {x0.x, x0.y, x0.z, x0.w, x1.x, x1.y, x1.z, x1.w};
    AB ah, al;
    build_hl(xv, ah, al);
    mfma3(ah, al, WhI, WlI, q, lane, acc);
  }
  float cc = *cptr, sc = sqrtf(cc);
  {
    float bj[8];
    bias8(nullptr, ml, bj);
#pragma unroll
    for (int r = 0; r < 4; r++) {
      int rowD = m0 + quad * 4 + r;
      float vs[8];
      row_vs<0>(acc, bj, r, vs);
      if (rowD < M) {
        store_T_row(vs, To, rowD, ml);
        store_P_row(vs, HHh + 64, ptF + 1, rowD, ml, cc, sc, PS_SCALE);
      }
#pragma unroll
      for (int t = 0; t < 8; t++) tile[wid][quad * 4 + r][t * 16 + ml] = vs[t];
    }
  }
#pragma unroll
  for (int t = 0; t < 8; t++) acc[t] = (f32x4){0.f, 0.f, 0.f, 0.f};
  gemm_lds(tile[wid], ml, quad, lane, WhA, WlA, acc);
  {
    float bj[8];
    bias8(attb, ml, bj);
#pragma unroll
    for (int r = 0; r < 4; r++) {
      int rowD = m0 + quad * 4 + r;
      float vs[8];
      row_vs<0>(acc, bj, r, vs);
      if (rowD < M) store_P_row(vs, HHh, ptF, rowD, ml, cc, sc, 1.f);
    }
  }
}

// ---------------- fused MLP pair (+ next layer's att GEMM unless LAST) ----------------
template <int LAST>
__global__ __launch_bounds__(256) void k_mlp3(
    const u32* __restrict__ A32, const u16* __restrict__ Wha, const u16* __restrict__ Wla,
    const float* __restrict__ ba, const u16* __restrict__ Whb, const u16* __restrict__ Wlb,
    const float* __restrict__ bb, const u16* __restrict__ WhA, const u16* __restrict__ WlA,
    const float* __restrict__ attb, u32* __restrict__ To, u32* __restrict__ HHh,
    float* __restrict__ ptF, const float* __restrict__ cptr, int M) {
  __shared__ float tile[4][16][129];
  int lane = threadIdx.x & 63, wid = threadIdx.x >> 6;
  int m0 = blockIdx.x * 64 + wid * 16;
  int ml = lane & 15, quad = lane >> 4;
  int mld = m0 + ml;
  f32x4 acc[8];
#pragma unroll
  for (int t = 0; t < 8; t++) acc[t] = (f32x4){0.f, 0.f, 0.f, 0.f};
  gemm_packhl(A32, mld, Wha, Wla, lane, quad, acc);
  {
    float bj[8];
    bias8(ba, ml, bj);
#pragma unroll
    for (int r = 0; r < 4; r++) {
      float vs[8];
      row_vs<1>(acc, bj, r, vs);
#pragma unroll
      for (int t = 0; t < 8; t++) tile[wid][quad * 4 + r][t * 16 + ml] = vs[t];
    }
  }
#pragma unroll
  for (int t = 0; t < 8; t++) acc[t] = (f32x4){0.f, 0.f, 0.f, 0.f};
  gemm_lds(tile[wid], ml, quad, lane, Whb, Wlb, acc);
  float cc = 1.f, sc = 1.f;
  if (!LAST) {
    cc = *cptr;
    sc = sqrtf(cc);
  }
  {
    float bj[8];
    bias8(bb, ml, bj);
#pragma unroll
    for (int r = 0; r < 4; r++) {
      int rowD = m0 + quad * 4 + r;
      float vs[8];
      row_vs<1>(acc, bj, r, vs);
      if (rowD < M) store_T_row(vs, To, rowD, ml);
      if (!LAST) {
        if (rowD < M) store_P_row(vs, HHh + 64, ptF + 1, rowD, ml, cc, sc, PS_SCALE);
#pragma unroll
        for (int t = 0; t < 8; t++) tile[wid][quad * 4 + r][t * 16 + ml] = vs[t];
      }
    }
  }
  if (!LAST) {
#pragma unroll
    for (int t = 0; t < 8; t++) acc[t] = (f32x4){0.f, 0.f, 0.f, 0.f};
    gemm_lds(tile[wid], ml, quad, lane, WhA, WlA, acc);
    float bj[8];
    bias8(attb, ml, bj);
#pragma unroll
    for (int r = 0; r < 4; r++) {
      int rowD = m0 + quad * 4 + r;
      float vs[8];
      row_vs<0>(acc, bj, r, vs);
      if (rowD < M) store_P_row(vs, HHh, ptF, rowD, ml, cc, sc, 1.f);
    }
  }
}

// ---------------- fused attention + aggregation, 8-lane edge groups ----------------
// HHh row (128 u32): [0..63] HL half2 (cols s, s+64); [64..127] H half2 * 2^-6.
// ptHH[node] = (time(HL), time(H)*2^-6).
__global__ __launch_bounds__(256) void k_agg_o(const u32* __restrict__ HHh,
                                               const float2* __restrict__ ptHH,
                                               const u32* __restrict__ T,
                                               const int* __restrict__ rowp,
                                               const int* __restrict__ dsts,
                                               const float* __restrict__ epsp,
                                               const float* __restrict__ cptr,
                                               u32* __restrict__ Tout, int n) {
  int node = blockIdx.x * 4 + (threadIdx.x >> 6);
  int lane = threadIdx.x & 63;
  if (node >= n) return;
  int o = lane & 7, g = lane >> 3;
  float c = *cptr, sc = sqrtf(c), rcpc = 1.f / c;
  bool sc1 = (sc == 1.0f);  // att = exp(-sc*acosh(v)) == 1/w when sc==1
  float eps = *epsp;
  const u32* arow = HHh + (size_t)node * 128 + o * 8;
  uint4 a0 = *(const uint4*)arow;
  uint4 a1 = *(const uint4*)(arow + 4);
  u32 apk[8] = {a0.x, a0.y, a0.z, a0.w, a1.x, a1.y, a1.z, a1.w};
  float pts = ptHH[node].x;
  int e0 = rowp[node], e1 = rowp[node + 1];
  int iters = (e1 - e0 + 7) >> 3;
  h2f mpk[8];
  {
    UH z;
    z.u = 0;
#pragma unroll
    for (int j = 0; j < 8; j++) mpk[j] = z.h;
  }
  float mt = 0.f;
#pragma unroll 2
  for (int it = 0; it < iters; it++) {
    int e = e0 + it * 8 + g;
    bool ve = e < e1;
    int d = dsts[ve ? e : e0];
    const u32* rb = HHh + (size_t)d * 128 + o * 8;
    uint4 b0 = *(const uint4*)rb;
    uint4 b1 = *(const uint4*)(rb + 4);
    uint4 h0 = *(const uint4*)(rb + 64);
    uint4 h1 = *(const uint4*)(rb + 68);
    float2 pp = ptHH[d];
    u32 bw[8] = {b0.x, b0.y, b0.z, b0.w, b1.x, b1.y, b1.z, b1.w};
    float dot = 0.f;
#pragma unroll
    for (int j = 0; j < 8; j++) dot = fdot2h(apk[j], bw[j], dot);
    dot += __shfl_xor(dot, 1);
    dot += __shfl_xor(dot, 2);
    dot += __shfl_xor(dot, 4);
    float valv = fmaxf((pts * pp.x - dot) * rcpc, 1.f + EPSH);
    float w = valv + sqrtf(fmaf(valv, valv, -1.f));
    float att;
    if (sc1)
      att = frcp(w);
    else
      att = exp2f(-sc * __log2f(w));
    att = ve ? att : 0.f;
    UH att2;
    att2.u = pk2h(att, att);
    u32 hw[8] = {h0.x, h0.y, h0.z, h0.w, h1.x, h1.y, h1.z, h1.w};
#pragma unroll
    for (int j = 0; j < 8; j++) {
      UH hv;
      hv.u = hw[j];
      mpk[j] = att2.h * hv.h + mpk[j];  // v_pk_fma_f16
    }
    mt = fmaf(att, pp.y, mt);
  }
  // cross-group reduce (offsets 8,16,32) -> all 8 g-copies identical per o
#pragma unroll
  for (int off = 8; off <= 32; off <<= 1) {
#pragma unroll
    for (int j = 0; j < 8; j++) {
      UH v;
      v.h = mpk[j];
      UH s;
      s.u = (u32)__shfl_xor((int)v.u, off);
      mpk[j] = v.h + s.h;
    }
    mt += __shfl_xor(mt, off);
  }
  // lsq over the full spatial vector (slots partitioned across o; reduce 1,2,4)
  float lp = 0.f;
#pragma unroll
  for (int j = 0; j < 8; j++) {
    float lo = (float)mpk[j][0], hi = (float)mpk[j][1];
    lp = fmaf(lo, lo, lp);
    lp = fmaf(hi, hi, lp);
  }
  lp += __shfl_xor(lp, 1);
  lp += __shfl_xor(lp, 2);
  lp += __shfl_xor(lp, 4);
  float lsq = lp;
  float neg_inner = mt * mt - lsq;
  float denom = sqrtf(fmaxf(neg_inner, 1e-9f));
  float r = sc / denom;
  float ssq = r * r * lsq;
  float agg0 = sqrtf(c + ssq);
  float ynA = fmaxf(sqrtf(ssq), 1e-9f);
  float v2 = fmaxf(agg0 / sc, 1.f + EPSH);
  float dA = sc * 0.69314718056f * __log2f(v2 + sqrtf(v2 * v2 - 1.f));
  float sca = dA * r / ynA;
  // all-lane epilogue: lane (o,g) owns slot s = o*8+g in each half-row
  int s = o * 8 + g;
  u32 msel = 0;
#pragma unroll
  for (int j = 0; j < 8; j++) {
    UH v;
    v.h = mpk[j];
    if (j == g) msel = v.u;
  }
  UH mm;
  mm.u = msel;
  float mlo = (float)mm.h[0], mhi = (float)mm.h[1];
  float oe = 1.f + eps;
  u32 t0 = T[(size_t)node * 128 + s];
  u32 t1 = T[(size_t)node * 128 + 64 + s];
  Tout[(size_t)node * 128 + s] = packhl(fmaf(sca, mlo, oe * rec(t0)));
  Tout[(size_t)node * 128 + 64 + s] = packhl(fmaf(sca, mhi, oe * rec(t1)));
}

// ---------------- pooling ----------------
__global__ void k_pool(const u32* __restrict__ U, const int* __restrict__ gptr,
                       float* __restrict__ out, int layer) {
  int g = blockIdx.x;
  int c = threadIdx.x;  // 0..127
  int s = gptr[g], e = gptr[g + 1];
  float acc = 0.f;
  if (c > 0) {
    const u32* up = U + (c - 1);
    int i = s;
    float a0 = 0.f, a1 = 0.f, a2 = 0.f, a3 = 0.f;
    for (; i + 3 < e; i += 4) {
      a0 += rec(up[(size_t)i * 128]);
      a1 += rec(up[(size_t)(i + 1) * 128]);
      a2 += rec(up[(size_t)(i + 2) * 128]);
      a3 += rec(up[(size_t)(i + 3) * 128]);
    }
    for (; i < e; i++) a0 += rec(up[(size_t)i * 128]);
    acc = (a0 + a1) + (a2 + a3);
  }
  out[(size_t)g * 256 + layer * 128 + c] = acc;
}

// ---------------- launch ----------------
extern "C" void kernel_launch(void* const* d_in, const int* in_sizes, int n_in, void* d_out,
                              int out_size, void* d_ws, size_t ws_size, hipStream_t stream) {
  const float* x = (const float*)d_in[0];
  const float* cptr = (const float*)d_in[1];
  const float* w_in = (const float*)d_in[2];
  const float* att_w = (const float*)d_in[3];
  const float* att_b = (const float*)d_in[4];
  const float* epsv = (const float*)d_in[5];
  const float* mlp_w = (const float*)d_in[6];
  const float* mlp_b = (const float*)d_in[7];
  const int* ei = (const int*)d_in[8];
  const int* batch = (const int*)d_in[9];
  const int* srcp = ei;
  const int* dstp = ei + EE;
  float* out = (float*)d_out;

  u32* ws = (u32*)d_ws;
  u16* Wfh = (u16*)ws;  // WF_TOT u16
  u16* Wfl = Wfh + WF_TOT;
  int* deg = (int*)(ws + 126976);  // N
  int* rowp = deg + NN;            // N+1
  int* cursor = rowp + NN + 1;     // N
  int* gptr = cursor + NN;         // G+1
  int* dsts = gptr + GG + 1;       // E
  size_t o1 = (size_t)((u32*)(dsts + EE) - ws);
  o1 = (o1 + 3) & ~(size_t)3;
  float2* ptHH = (float2*)(ws + o1);   // NNP float2
  u32* HHh = ws + o1 + 2 * NNP;        // NNP*128 (HL | H), half2 slots
  u32* A32 = HHh + (size_t)NNP * 128;  // NNP*128 packhl tangent
  u32* B32 = A32 + (size_t)NNP * 128;  // NNP*128

  const int EW = 12500;  // agg: 4 nodes/block
  const int GEMMG = (NN + 63) / 64;
  const int SETUPG = SETUP_PREP_BLKS + SETUP_GPTR_BLKS + (EE + 255) / 256;
  float* ptF = (float*)ptHH;

  (void)hipMemsetAsync(deg, 0, NN * sizeof(int), stream);
  k_setup<<<SETUPG, 256, 0, stream>>>(att_w, mlp_w, w_in, Wfh, Wfl, batch, gptr, srcp, deg);
  k_scan_excl<<<1, 1024, 0, stream>>>(deg, NN, rowp, cursor);
  k_scatter<<<(EE + 255) / 256, 256, 0, stream>>>(srcp, dstp, EE, cursor, dsts);

#define WH(m) (Wfh + 28672 + (m) * 16384)
#define WL(m) (Wfl + 28672 + (m) * 16384)

  // input GEMM + att0: T0 -> A32 ; H0 -> (HHh+64, ptF odd) ; HL0 -> (HHh, ptF even)
  k_gemm_in<<<GEMMG, 256, 0, stream>>>(x, Wfh, Wfl, WH(0), WL(0), att_b, A32, HHh, ptF, cptr, NN);

  // ---- layer 0 ----
  k_agg_o<<<EW, 256, 0, stream>>>(HHh, ptHH, A32, rowp, dsts, epsv + 0, cptr, B32, NN);
  k_mlp3<0><<<GEMMG, 256, 0, stream>>>(B32, WH(2), WL(2), mlp_b + 0 * DD, WH(3), WL(3),
                                       mlp_b + 1 * DD, WH(1), WL(1), att_b + DD, A32, HHh, ptF,
                                       cptr, NN);
  k_pool<<<GG, 128, 0, stream>>>(A32, gptr, out, 0);

  // ---- layer 1 ----
  k_agg_o<<<EW, 256, 0, stream>>>(HHh, ptHH, A32, rowp, dsts, epsv + 1, cptr, B32, NN);
  k_mlp3<1><<<GEMMG, 256, 0, stream>>>(B32, WH(4), WL(4), mlp_b + 2 * DD, WH(5), WL(5),
                                       mlp_b + 3 * DD, nullptr, nullptr, nullptr, B32, nullptr,
                                       nullptr, cptr, NN);
  k_pool<<<GG, 128, 0, stream>>>(B32, gptr, out, 1);
}